// Round 22
// baseline (258.442 us; speedup 1.0000x reference)
//
#include <hip/hip_runtime.h>
#include <hip/hip_bf16.h>
#include <cstdint>
#include <cstddef>

#define B_ 4
#define T_ 2048
#define C_ 768
#define H_ 12
#define D_ 64
#define FF_ 3072

typedef __attribute__((ext_vector_type(4))) float f32x4;
typedef __attribute__((ext_vector_type(8))) short s16x8;
typedef __attribute__((ext_vector_type(4))) short s16x4;

static __device__ __forceinline__ short f2bf(float f) {
  union { float fv; unsigned u; } v; v.fv = f;
  unsigned r = v.u + 0x7FFFu + ((v.u >> 16) & 1u);  // RNE
  return (short)(r >> 16);
}

static __device__ __forceinline__ unsigned pkbf2(float a, float b) {
  __hip_bfloat162 h = __float22bfloat162_rn(make_float2(a, b));  // v_cvt_pk_bf16_f32
  union { __hip_bfloat162 h2; unsigned u; } v; v.h2 = h;
  return v.u;
}

// ---------- merged weight convert+transpose: 4 weights in ONE launch ----------
__global__ __launch_bounds__(256) void wconv_all(
    const float* __restrict__ in0, short* __restrict__ o0,
    const float* __restrict__ in1, short* __restrict__ o1,
    const float* __restrict__ in2, short* __restrict__ o2,
    const float* __restrict__ in3, short* __restrict__ o3) {
  __shared__ float tile[32][33];
  int idx = blockIdx.x;
  const float* in; short* out; int K, N, tk, tn;
  if (idx < 1728)      { in = in0; out = o0; K = 768;  N = 2304; int l = idx;        tk = (l % 24) * 32; tn = (l / 24) * 32; }
  else if (idx < 2304) { in = in1; out = o1; K = 768;  N = 768;  int l = idx - 1728; tk = (l % 24) * 32; tn = (l / 24) * 32; }
  else if (idx < 4608) { in = in2; out = o2; K = 768;  N = 3072; int l = idx - 2304; tk = (l % 24) * 32; tn = (l / 24) * 32; }
  else                 { in = in3; out = o3; K = 3072; N = 768;  int l = idx - 4608; tk = (l % 96) * 32; tn = (l / 96) * 32; }
  int lx = threadIdx.x & 31, ly = threadIdx.x >> 5;
#pragma unroll
  for (int i = 0; i < 4; ++i)
    tile[ly + i * 8][lx] = in[(size_t)(tk + ly + i * 8) * N + tn + lx];
  __syncthreads();
#pragma unroll
  for (int i = 0; i < 4; ++i)
    out[(size_t)(tn + ly + i * 8) * K + tk + lx] = f2bf(tile[lx][ly + i * 8]);
}

// ---------- layernorm: one WAVE per row, float4 loads, in-wave shfl reduce ----------
__global__ __launch_bounds__(256) void ln_kernel(const float* __restrict__ x,
                                                 const float* __restrict__ w,
                                                 const float* __restrict__ b,
                                                 short* __restrict__ out) {
  int lane = threadIdx.x & 63, wv = threadIdx.x >> 6;
  int row = (blockIdx.x << 2) | wv;
  const float* xr = x + (size_t)row * 768 + lane * 12;
  f32x4 a0 = *(const f32x4*)(xr);
  f32x4 a1 = *(const f32x4*)(xr + 4);
  f32x4 a2 = *(const f32x4*)(xr + 8);
  float s = (a0[0] + a0[1] + a0[2] + a0[3]) + (a1[0] + a1[1] + a1[2] + a1[3]) +
            (a2[0] + a2[1] + a2[2] + a2[3]);
#pragma unroll
  for (int o = 32; o > 0; o >>= 1) s += __shfl_xor(s, o);
  float mean = s * (1.f / 768.f);
  float q = 0.f;
#pragma unroll
  for (int j = 0; j < 4; ++j) { float d = a0[j] - mean; q += d * d; }
#pragma unroll
  for (int j = 0; j < 4; ++j) { float d = a1[j] - mean; q += d * d; }
#pragma unroll
  for (int j = 0; j < 4; ++j) { float d = a2[j] - mean; q += d * d; }
#pragma unroll
  for (int o = 32; o > 0; o >>= 1) q += __shfl_xor(q, o);
  float rstd = rsqrtf(q * (1.f / 768.f) + 1e-5f);
  const float* wp = w + lane * 12;
  const float* bp = b + lane * 12;
  f32x4 w0 = *(const f32x4*)(wp), w1 = *(const f32x4*)(wp + 4), w2 = *(const f32x4*)(wp + 8);
  f32x4 b0 = *(const f32x4*)(bp), b1 = *(const f32x4*)(bp + 4), b2 = *(const f32x4*)(bp + 8);
  short* orow = out + (size_t)row * 768 + lane * 12;
  s16x4 o0, o1, o2;
#pragma unroll
  for (int j = 0; j < 4; ++j) {
    o0[j] = f2bf((a0[j] - mean) * rstd * w0[j] + b0[j]);
    o1[j] = f2bf((a1[j] - mean) * rstd * w1[j] + b1[j]);
    o2[j] = f2bf((a2[j] - mean) * rstd * w2[j] + b2[j]);
  }
  *(s16x4*)(orow) = o0;
  *(s16x4*)(orow + 4) = o1;
  *(s16x4*)(orow + 8) = o2;
}

// ---------- GEMM 128x128, BK=32, DEPTH-3 counted-vmcnt pipeline ----------
// R18's depth-2 was mildly positive; single prefetch tile doesn't fully cover
// ~500cy DMA latency at 3-4 blocks/CU. 3 buffers (48KB, 3 blocks/CU), tiles
// t+1 AND t+2 in flight across barriers -> vmcnt(8); exact tail (8->4->0).
template <int MODE>
__global__ __launch_bounds__(256) void gemm_bt(
    const short* __restrict__ A, const short* __restrict__ Bt,
    const float* __restrict__ bias, const float* __restrict__ res,
    void* __restrict__ out,
    short* __restrict__ dq, short* __restrict__ dk, short* __restrict__ dv,
    int M, int N, int K) {
  __shared__ short As[3][128 * 32];
  __shared__ short Bs[3][128 * 32];
  int tid = threadIdx.x;
  int lane = tid & 63;
  int wm = tid >> 7;
  int wn = (tid >> 6) & 1;
  const short* Ab = A + (size_t)blockIdx.x * 128 * K;
  const short* Bb = Bt + (size_t)blockIdx.y * 128 * K;
  f32x4 acc[4][4] = {};
  int i15 = lane & 15, g8 = (lane >> 4) << 3;
  int nk = K >> 5;
  int r0 = tid >> 2, kc = (tid & 3) << 3;

  auto stage = [&](int buf, int kt) {
    int kof = kt << 5;
    __builtin_amdgcn_global_load_lds(
        (const __attribute__((address_space(1))) unsigned*)(Ab + (size_t)r0 * K + kof + kc),
        (__attribute__((address_space(3))) unsigned*)(&As[buf][tid * 8]), 16, 0, 0);
    __builtin_amdgcn_global_load_lds(
        (const __attribute__((address_space(1))) unsigned*)(Bb + (size_t)r0 * K + kof + kc),
        (__attribute__((address_space(3))) unsigned*)(&Bs[buf][tid * 8]), 16, 0, 0);
    __builtin_amdgcn_global_load_lds(
        (const __attribute__((address_space(1))) unsigned*)(Ab + (size_t)(r0 + 64) * K + kof + kc),
        (__attribute__((address_space(3))) unsigned*)(&As[buf][(tid + 256) * 8]), 16, 0, 0);
    __builtin_amdgcn_global_load_lds(
        (const __attribute__((address_space(1))) unsigned*)(Bb + (size_t)(r0 + 64) * K + kof + kc),
        (__attribute__((address_space(3))) unsigned*)(&Bs[buf][(tid + 256) * 8]), 16, 0, 0);
  };

  stage(0, 0);
  stage(1, 1);
  stage(2, 2);
  int cur = 0;
  for (int kt = 0; kt < nk; ++kt) {
    if (kt + 2 < nk)
      asm volatile("s_waitcnt vmcnt(8)" ::: "memory");   // kt done; kt+1,kt+2 in flight
    else if (kt + 1 < nk)
      asm volatile("s_waitcnt vmcnt(4)" ::: "memory");
    else
      asm volatile("s_waitcnt vmcnt(0)" ::: "memory");
    __builtin_amdgcn_s_barrier();
    __builtin_amdgcn_sched_barrier(0);
    s16x8 af[4], bfr[4];
#pragma unroll
    for (int m = 0; m < 4; ++m)
      af[m] = *(const s16x8*)(&As[cur][(wm * 64 + m * 16 + i15) * 32 + g8]);
#pragma unroll
    for (int n = 0; n < 4; ++n)
      bfr[n] = *(const s16x8*)(&Bs[cur][(wn * 64 + n * 16 + i15) * 32 + g8]);
    __builtin_amdgcn_s_setprio(1);
#pragma unroll
    for (int m = 0; m < 4; ++m)
#pragma unroll
      for (int n = 0; n < 4; ++n)
        acc[m][n] = __builtin_amdgcn_mfma_f32_16x16x32_bf16(af[m], bfr[n], acc[m][n], 0, 0, 0);
    __builtin_amdgcn_s_setprio(0);
    __builtin_amdgcn_sched_barrier(0);
    __builtin_amdgcn_s_barrier();
    if (kt + 3 < nk) stage(cur, kt + 3);     // reuse just-consumed buffer
    cur = (cur == 2) ? 0 : cur + 1;
  }
  int row0 = blockIdx.x * 128 + wm * 64;
  int col0 = blockIdx.y * 128 + wn * 64;
  int g4 = (lane >> 4) << 2;
#pragma unroll
  for (int m = 0; m < 4; ++m) {
#pragma unroll
    for (int n = 0; n < 4; ++n) {
      int col = col0 + n * 16 + i15;
      float bv = bias[col];
      float v4[4];
#pragma unroll
      for (int r = 0; r < 4; ++r) v4[r] = acc[m][n][r] + bv;
      int rbase = row0 + m * 16 + g4;
      if constexpr (MODE == 0) {
        int sect = col / 768;            // 0=q 1=k 2=v
        int wi = col - sect * 768;
        int hh = wi >> 6, dd = wi & 63;
        int bb = rbase >> 11, tt = rbase & 2047;
        if (sect == 2) {
          s16x4 o4;
#pragma unroll
          for (int r = 0; r < 4; ++r) o4[r] = f2bf(v4[r]);
          *(s16x4*)(dv + ((size_t)(bb * H_ + hh) * D_ + dd) * T_ + tt) = o4;
        } else {
          short* dst = (sect == 0 ? dq : dk) + ((size_t)(bb * H_ + hh) * T_ + tt) * D_ + dd;
          float sc = sect == 0 ? 0.18033688f : 1.f;   // 0.125 * log2(e)
#pragma unroll
          for (int r = 0; r < 4; ++r) dst[(size_t)r * D_] = f2bf(v4[r] * sc);
        }
      } else {
#pragma unroll
        for (int r = 0; r < 4; ++r)
          ((short*)out)[(size_t)(rbase + r) * N + col] = f2bf(v4[r] > 0.f ? v4[r] : 0.f);
      }
    }
  }
}

// ---------- GEMM 64x128, BK=64 two-panel, 4-wave, depth-2 counted-vmcnt (R21-proven) ----------
__global__ __launch_bounds__(256) void gemm64_res(
    const short* __restrict__ A, const short* __restrict__ Bt,
    const float* __restrict__ bias, const float* __restrict__ res,
    float* __restrict__ out, int M, int N, int K) {
  __shared__ short As[2][2][64 * 32];
  __shared__ short Bs[2][2][128 * 32];
  int tid = threadIdx.x;
  int lane = tid & 63;
  int wv = tid >> 6;                   // wave owns cols wv*32..wv*32+31
  const short* Ab = A + (size_t)blockIdx.x * 64 * K;
  const short* Bb = Bt + (size_t)blockIdx.y * 128 * K;
  f32x4 acc[4][2] = {};
  int i15 = lane & 15, g8 = (lane >> 4) << 3;
  int nk = K >> 6;

  auto stage = [&](int buf, int kt) {
    int kof = kt << 6;
#pragma unroll
    for (int i = 0; i < 2; ++i) {      // A: 64x64 = 512 chunks, 2/thread
      int c = tid + i * 256;
      int pan = c >> 8, sp = c & 255;
      int row = sp >> 2, kk = ((sp & 3) << 3) + (pan << 5);
      __builtin_amdgcn_global_load_lds(
          (const __attribute__((address_space(1))) unsigned*)(Ab + (size_t)row * K + kof + kk),
          (__attribute__((address_space(3))) unsigned*)(&As[buf][pan][sp * 8]), 16, 0, 0);
    }
#pragma unroll
    for (int i = 0; i < 4; ++i) {      // B: 128x64 = 1024 chunks, 4/thread
      int c = tid + i * 256;
      int pan = c >> 9, sp = c & 511;
      int row = sp >> 2, kk = ((sp & 3) << 3) + (pan << 5);
      __builtin_amdgcn_global_load_lds(
          (const __attribute__((address_space(1))) unsigned*)(Bb + (size_t)row * K + kof + kk),
          (__attribute__((address_space(3))) unsigned*)(&Bs[buf][pan][sp * 8]), 16, 0, 0);
    }
  };

  stage(0, 0);
  if (nk > 1) stage(1, 1);
  int cur = 0;
  for (int kt = 0; kt < nk; ++kt) {
    if (kt + 1 < nk)
      asm volatile("s_waitcnt vmcnt(6)" ::: "memory");   // tile kt staged; kt+1 in flight
    else
      asm volatile("s_waitcnt vmcnt(0)" ::: "memory");
    __builtin_amdgcn_s_barrier();
    __builtin_amdgcn_sched_barrier(0);
#pragma unroll
    for (int h = 0; h < 2; ++h) {
      s16x8 af[4], bfr[2];
#pragma unroll
      for (int m = 0; m < 4; ++m)
        af[m] = *(const s16x8*)(&As[cur][h][(m * 16 + i15) * 32 + g8]);
#pragma unroll
      for (int n = 0; n < 2; ++n)
        bfr[n] = *(const s16x8*)(&Bs[cur][h][(wv * 32 + n * 16 + i15) * 32 + g8]);
      __builtin_amdgcn_s_setprio(1);
#pragma unroll
      for (int m = 0; m < 4; ++m)
#pragma unroll
        for (int n = 0; n < 2; ++n)
          acc[m][n] = __builtin_amdgcn_mfma_f32_16x16x32_bf16(af[m], bfr[n], acc[m][n], 0, 0, 0);
      __builtin_amdgcn_s_setprio(0);
    }
    __builtin_amdgcn_sched_barrier(0);
    __builtin_amdgcn_s_barrier();
    if (kt + 2 < nk) stage(cur, kt + 2);
    cur ^= 1;
  }
  int row0 = blockIdx.x * 64;
  int col0 = blockIdx.y * 128 + wv * 32;
  int g4 = (lane >> 4) << 2;
#pragma unroll
  for (int m = 0; m < 4; ++m) {
#pragma unroll
    for (int n = 0; n < 2; ++n) {
      int col = col0 + n * 16 + i15;
      float bv = bias[col];
      int rbase = row0 + m * 16 + g4;
#pragma unroll
      for (int r = 0; r < 4; ++r)
        out[(size_t)(rbase + r) * N + col] =
            acc[m][n][r] + bv + res[(size_t)(rbase + r) * N + col];
    }
  }
}

// ---------- causal flash attention: LDS-DMA staged + uniform pair blocks + MFMA-ones denom ----------
// (R17 structure - best measured: 70.3 us. Unchanged.)
__global__ __launch_bounds__(256) void attn_kernel(const short* __restrict__ Qb,
                                                   const short* __restrict__ Kb,
                                                   const short* __restrict__ VTb,
                                                   short* __restrict__ Ob) {
  __shared__ short Ks[2][4096];
  __shared__ short Vs[2][4096];
  int i = blockIdx.x;
  int c = i & 7, j = i >> 3;
  int p = j & 15, gy = j >> 4;
  int bh = c + (gy << 3);
  int bb = bh / H_, hh = bh - bb * H_;
  int tid = threadIdx.x, lane = tid & 63, wv = tid >> 6;
  const short* Qp = Qb + (size_t)bh * T_ * D_;
  const short* Kp = Kb + (size_t)bh * T_ * D_;
  const short* Vp = VTb + (size_t)bh * D_ * T_;
  int i15 = lane & 15, g = lane >> 4, g8 = g << 3;
  int keyA0 = ((i15 >> 2) << 3) + (i15 & 3);
  int keyB0 = keyA0 + 4;
  int fA = (keyA0 & 7) ^ ((keyA0 & 8) >> 1);
  int fB = (keyB0 & 7) ^ ((keyB0 & 8) >> 1);
  int fV = (i15 & 7) ^ ((i15 & 8) >> 1);
  int oA[2], oB[2], oV[2];
#pragma unroll
  for (int h = 0; h < 2; ++h) {
    oA[h] = keyA0 * 64 + (((h * 4 + g) ^ fA) << 3);
    oB[h] = keyB0 * 64 + (((h * 4 + g) ^ fB) << 3);
    oV[h] = i15 * 64 + (((h * 4 + g) ^ fV) << 3);
  }
  int n0 = p + 1;
  s16x8 ones;
#pragma unroll
  for (int r = 0; r < 8; ++r) ones[r] = (short)0x3F80;   // bf16 1.0
  s16x8 qf0, qf1;
  f32x4 oacc[4] = {};
  f32x4 lacc = {};
  int qrow = 0;

  auto loadQ = [&](int qb) {
    qrow = (qb << 6) + wv * 16 + i15;
    qf0 = *(const s16x8*)(Qp + (size_t)qrow * D_ + g8);
    qf1 = *(const s16x8*)(Qp + (size_t)qrow * D_ + 32 + g8);
  };
  auto stage = [&](int buf, int t) {
    int k0 = t << 6;
#pragma unroll
    for (int qq = 0; qq < 2; ++qq) {
      int m = tid + qq * 256;
      int r = m >> 3, cd = m & 7;
      int cs = cd ^ ((r & 7) ^ ((r & 8) >> 1));
      __builtin_amdgcn_global_load_lds(
          (const __attribute__((address_space(1))) unsigned*)(Kp + (size_t)(k0 + r) * D_ + (cs << 3)),
          (__attribute__((address_space(3))) unsigned*)(&Ks[buf][m * 8]), 16, 0, 0);
      __builtin_amdgcn_global_load_lds(
          (const __attribute__((address_space(1))) unsigned*)(Vp + (size_t)r * T_ + k0 + (cs << 3)),
          (__attribute__((address_space(3))) unsigned*)(&Vs[buf][m * 8]), 16, 0, 0);
    }
  };
  auto finalize = [&]() {
    float inv = 1.f / lacc[0];
    short* op = Ob + ((size_t)(bb * T_ + qrow)) * C_ + hh * D_ + (g << 2);
#pragma unroll
    for (int mt = 0; mt < 4; ++mt) {
      s16x4 o4;
#pragma unroll
      for (int r = 0; r < 4; ++r) o4[r] = f2bf(oacc[mt][r] * inv);
      *(s16x4*)(op + mt * 16) = o4;
    }
  };

  loadQ(p);
  stage(0, 0);
  __syncthreads();
  int cur = 0;
#pragma unroll 1
  for (int gt = 0; gt < 33; ++gt) {
    if (gt + 1 < 33) {
      int nkt = (gt + 1 < n0) ? (gt + 1) : (gt + 1 - n0);
      stage(cur ^ 1, nkt);
    }
    int kt = (gt < n0) ? gt : gt - n0;
    int nt = (gt < n0) ? n0 : 32 - p;
    bool diag = (kt == nt - 1);
    int k0 = kt << 6;
    const short* KB = &Ks[cur][0];
    const short* VB = &Vs[cur][0];
#pragma unroll
    for (int ks = 0; ks < 2; ++ks) {
      if (!(ks == 1 && diag && wv < 2)) {
        s16x8 ka0 = *(const s16x8*)(KB + (ks << 11) + oA[0]);
        s16x8 ka1 = *(const s16x8*)(KB + (ks << 11) + oA[1]);
        s16x8 kb0 = *(const s16x8*)(KB + (ks << 11) + oB[0]);
        s16x8 kb1 = *(const s16x8*)(KB + (ks << 11) + oB[1]);
        f32x4 sA = {}, sB = {};
        __builtin_amdgcn_s_setprio(1);
        sA = __builtin_amdgcn_mfma_f32_16x16x32_bf16(ka0, qf0, sA, 0, 0, 0);
        sA = __builtin_amdgcn_mfma_f32_16x16x32_bf16(ka1, qf1, sA, 0, 0, 0);
        sB = __builtin_amdgcn_mfma_f32_16x16x32_bf16(kb0, qf0, sB, 0, 0, 0);
        sB = __builtin_amdgcn_mfma_f32_16x16x32_bf16(kb1, qf1, sB, 0, 0, 0);
        __builtin_amdgcn_s_setprio(0);
        int kb = k0 + (ks << 5) + g8;
        float sa[8];
        bool needmask = diag && ((wv < 2) == (ks == 0));
        if (needmask) {
#pragma unroll
          for (int r = 0; r < 4; ++r) {
            sa[r]     = (kb + r     <= qrow) ? sA[r] : -1e30f;
            sa[4 + r] = (kb + 4 + r <= qrow) ? sB[r] : -1e30f;
          }
        } else {
#pragma unroll
          for (int r = 0; r < 4; ++r) { sa[r] = sA[r]; sa[4 + r] = sB[r]; }
        }
        float pv[8];
#pragma unroll
        for (int r = 0; r < 8; ++r) pv[r] = exp2f(sa[r]);
        union { unsigned u[4]; s16x8 v; } pf;
        pf.u[0] = pkbf2(pv[0], pv[1]);
        pf.u[1] = pkbf2(pv[2], pv[3]);
        pf.u[2] = pkbf2(pv[4], pv[5]);
        pf.u[3] = pkbf2(pv[6], pv[7]);
        s16x8 vf0 = *(const s16x8*)(VB + 0    + oV[ks]);
        s16x8 vf1 = *(const s16x8*)(VB + 1024 + oV[ks]);
        s16x8 vf2 = *(const s16x8*)(VB + 2048 + oV[ks]);
        s16x8 vf3 = *(const s16x8*)(VB + 3072 + oV[ks]);
        __builtin_amdgcn_s_setprio(1);
        oacc[0] = __builtin_amdgcn_mfma_f32_16x16x32_bf16(vf0, pf.v, oacc[0], 0, 0, 0);
        oacc[1] = __builtin_amdgcn_mfma_f32_16x16x32_bf16(vf1, pf.v, oacc[1], 0, 0, 0);
        oacc[2] = __builtin_amdgcn_mfma_f32_16x16x32_bf16(vf2, pf.v, oacc[2], 0, 0, 0);
        oacc[3] = __builtin_amdgcn_mfma_f32_16x16x32_bf16(vf3, pf.v, oacc[3], 0, 0, 0);
        lacc = __builtin_amdgcn_mfma_f32_16x16x32_bf16(ones, pf.v, lacc, 0, 0, 0);
        __builtin_amdgcn_s_setprio(0);
      }
    }
    if (gt == n0 - 1) {                // sub0 complete: write it, start sub1
      finalize();
      loadQ(31 - p);
#pragma unroll
      for (int mt = 0; mt < 4; ++mt) oacc[mt] = f32x4{0.f, 0.f, 0.f, 0.f};
      lacc = f32x4{0.f, 0.f, 0.f, 0.f};
    }
    __syncthreads();
    cur ^= 1;
  }
  finalize();
}

extern "C" void kernel_launch(void* const* d_in, const int* in_sizes, int n_in,
                              void* d_out, int out_size, void* d_ws, size_t ws_size,
                              hipStream_t stream) {
  const float* x     = (const float*)d_in[0];
  const float* ln1_w = (const float*)d_in[1];
  const float* ln1_b = (const float*)d_in[2];
  const float* qkv_w = (const float*)d_in[3];
  const float* qkv_b = (const float*)d_in[4];
  const float* out_w = (const float*)d_in[5];
  const float* out_b = (const float*)d_in[6];
  const float* ln2_w = (const float*)d_in[7];
  const float* ln2_b = (const float*)d_in[8];
  const float* ff1_w = (const float*)d_in[9];
  const float* ff1_b = (const float*)d_in[10];
  const float* ff2_w = (const float*)d_in[11];
  const float* ff2_b = (const float*)d_in[12];

  char* ws = (char*)d_ws;
  short* Wqkv = (short*)(ws + 0);                       // [2304,768]
  short* Wout = (short*)(ws + 3538944);                 // [768,768]
  short* Wff1 = (short*)(ws + 4718592);                 // [3072,768]
  short* Wff2 = (short*)(ws + 9437184);                 // [768,3072]
  short* Hbuf = (short*)(ws + 14155776);                // [8192,768] bf16
  short* Qb   = (short*)(ws + 26738688);                // [B,H,T,D] bf16
  short* Kb   = Qb + 6291456;
  short* VT   = Kb + 6291456;                           // [B,H,D,T] bf16 (V stored transposed)
  short* Ob   = VT + 6291456;                           // [B,T,C] bf16
  short* FFH  = Qb;                                     // alias: [8192,3072] bf16 (Q/K/V/O dead)
  float* xout = (float*)d_out;                          // also x1 residual buffer

  wconv_all<<<6912, 256, 0, stream>>>(qkv_w, Wqkv, out_w, Wout, ff1_w, Wff1, ff2_w, Wff2);

  ln_kernel<<<2048, 256, 0, stream>>>(x, ln1_w, ln1_b, Hbuf);
  gemm_bt<0><<<dim3(64, 18), 256, 0, stream>>>(Hbuf, Wqkv, qkv_b, nullptr, nullptr,
                                               Qb, Kb, VT, 8192, 2304, 768);
  attn_kernel<<<768, 256, 0, stream>>>(Qb, Kb, VT, Ob);
  gemm64_res<<<dim3(128, 6), 256, 0, stream>>>(Ob, Wout, out_b, x, xout, 8192, 768, 768);
  ln_kernel<<<2048, 256, 0, stream>>>(xout, ln2_w, ln2_b, Hbuf);
  gemm_bt<2><<<dim3(64, 24), 256, 0, stream>>>(Hbuf, Wff1, ff1_b, nullptr, FFH,
                                               nullptr, nullptr, nullptr, 8192, 3072, 768);
  gemm64_res<<<dim3(128, 6), 256, 0, stream>>>(FFH, Wff2, ff2_b, xout, xout, 8192, 768, 3072);
}

// Round 23
// 253.805 us; speedup vs baseline: 1.0183x; 1.0183x over previous
//
#include <hip/hip_runtime.h>
#include <hip/hip_bf16.h>
#include <cstdint>
#include <cstddef>

#define B_ 4
#define T_ 2048
#define C_ 768
#define H_ 12
#define D_ 64
#define FF_ 3072

typedef __attribute__((ext_vector_type(4))) float f32x4;
typedef __attribute__((ext_vector_type(8))) short s16x8;
typedef __attribute__((ext_vector_type(4))) short s16x4;

static __device__ __forceinline__ short f2bf(float f) {
  union { float fv; unsigned u; } v; v.fv = f;
  unsigned r = v.u + 0x7FFFu + ((v.u >> 16) & 1u);  // RNE
  return (short)(r >> 16);
}

static __device__ __forceinline__ unsigned pkbf2(float a, float b) {
  __hip_bfloat162 h = __float22bfloat162_rn(make_float2(a, b));  // v_cvt_pk_bf16_f32
  union { __hip_bfloat162 h2; unsigned u; } v; v.h2 = h;
  return v.u;
}

// ---------- merged: 4x weight convert+transpose AND LayerNorm-1 in ONE launch ----------
// Segments (blockIdx.x):
//   [0,1728)     qkv_w  768x2304   [1728,2304) out_w 768x768
//   [2304,4608)  ff1_w  768x3072   [4608,6912) ff2_w 3072x768
//   [6912,8960)  LN1: 4 rows/block of x -> Hbuf (independent of wconv; both
//                feed the QKV GEMM, so fusing removes one launch boundary)
__global__ __launch_bounds__(256) void wconv_ln(
    const float* __restrict__ in0, short* __restrict__ o0,
    const float* __restrict__ in1, short* __restrict__ o1,
    const float* __restrict__ in2, short* __restrict__ o2,
    const float* __restrict__ in3, short* __restrict__ o3,
    const float* __restrict__ lnx, const float* __restrict__ lnw,
    const float* __restrict__ lnb, short* __restrict__ lno) {
  int idx = blockIdx.x;
  if (idx >= 6912) {                    // ---- LayerNorm segment ----
    int lane = threadIdx.x & 63, wv = threadIdx.x >> 6;
    int row = ((idx - 6912) << 2) | wv;
    const float* xr = lnx + (size_t)row * 768 + lane * 12;
    f32x4 a0 = *(const f32x4*)(xr);
    f32x4 a1 = *(const f32x4*)(xr + 4);
    f32x4 a2 = *(const f32x4*)(xr + 8);
    float s = (a0[0] + a0[1] + a0[2] + a0[3]) + (a1[0] + a1[1] + a1[2] + a1[3]) +
              (a2[0] + a2[1] + a2[2] + a2[3]);
#pragma unroll
    for (int o = 32; o > 0; o >>= 1) s += __shfl_xor(s, o);
    float mean = s * (1.f / 768.f);
    float q = 0.f;
#pragma unroll
    for (int j = 0; j < 4; ++j) { float d = a0[j] - mean; q += d * d; }
#pragma unroll
    for (int j = 0; j < 4; ++j) { float d = a1[j] - mean; q += d * d; }
#pragma unroll
    for (int j = 0; j < 4; ++j) { float d = a2[j] - mean; q += d * d; }
#pragma unroll
    for (int o = 32; o > 0; o >>= 1) q += __shfl_xor(q, o);
    float rstd = rsqrtf(q * (1.f / 768.f) + 1e-5f);
    const float* wp = lnw + lane * 12;
    const float* bp = lnb + lane * 12;
    f32x4 w0 = *(const f32x4*)(wp), w1 = *(const f32x4*)(wp + 4), w2 = *(const f32x4*)(wp + 8);
    f32x4 b0 = *(const f32x4*)(bp), b1 = *(const f32x4*)(bp + 4), b2 = *(const f32x4*)(bp + 8);
    short* orow = lno + (size_t)row * 768 + lane * 12;
    s16x4 o0v, o1v, o2v;
#pragma unroll
    for (int j = 0; j < 4; ++j) {
      o0v[j] = f2bf((a0[j] - mean) * rstd * w0[j] + b0[j]);
      o1v[j] = f2bf((a1[j] - mean) * rstd * w1[j] + b1[j]);
      o2v[j] = f2bf((a2[j] - mean) * rstd * w2[j] + b2[j]);
    }
    *(s16x4*)(orow) = o0v;
    *(s16x4*)(orow + 4) = o1v;
    *(s16x4*)(orow + 8) = o2v;
    return;
  }
  // ---- weight transpose segment ----
  __shared__ float tile[32][33];
  const float* in; short* out; int K, N, tk, tn;
  if (idx < 1728)      { in = in0; out = o0; K = 768;  N = 2304; int l = idx;        tk = (l % 24) * 32; tn = (l / 24) * 32; }
  else if (idx < 2304) { in = in1; out = o1; K = 768;  N = 768;  int l = idx - 1728; tk = (l % 24) * 32; tn = (l / 24) * 32; }
  else if (idx < 4608) { in = in2; out = o2; K = 768;  N = 3072; int l = idx - 2304; tk = (l % 24) * 32; tn = (l / 24) * 32; }
  else                 { in = in3; out = o3; K = 3072; N = 768;  int l = idx - 4608; tk = (l % 96) * 32; tn = (l / 96) * 32; }
  int lx = threadIdx.x & 31, ly = threadIdx.x >> 5;
#pragma unroll
  for (int i = 0; i < 4; ++i)
    tile[ly + i * 8][lx] = in[(size_t)(tk + ly + i * 8) * N + tn + lx];
  __syncthreads();
#pragma unroll
  for (int i = 0; i < 4; ++i)
    out[(size_t)(tn + ly + i * 8) * K + tk + lx] = f2bf(tile[lx][ly + i * 8]);
}

// ---------- layernorm: one WAVE per row, float4 loads, in-wave shfl reduce ----------
__global__ __launch_bounds__(256) void ln_kernel(const float* __restrict__ x,
                                                 const float* __restrict__ w,
                                                 const float* __restrict__ b,
                                                 short* __restrict__ out) {
  int lane = threadIdx.x & 63, wv = threadIdx.x >> 6;
  int row = (blockIdx.x << 2) | wv;
  const float* xr = x + (size_t)row * 768 + lane * 12;
  f32x4 a0 = *(const f32x4*)(xr);
  f32x4 a1 = *(const f32x4*)(xr + 4);
  f32x4 a2 = *(const f32x4*)(xr + 8);
  float s = (a0[0] + a0[1] + a0[2] + a0[3]) + (a1[0] + a1[1] + a1[2] + a1[3]) +
            (a2[0] + a2[1] + a2[2] + a2[3]);
#pragma unroll
  for (int o = 32; o > 0; o >>= 1) s += __shfl_xor(s, o);
  float mean = s * (1.f / 768.f);
  float q = 0.f;
#pragma unroll
  for (int j = 0; j < 4; ++j) { float d = a0[j] - mean; q += d * d; }
#pragma unroll
  for (int j = 0; j < 4; ++j) { float d = a1[j] - mean; q += d * d; }
#pragma unroll
  for (int j = 0; j < 4; ++j) { float d = a2[j] - mean; q += d * d; }
#pragma unroll
  for (int o = 32; o > 0; o >>= 1) q += __shfl_xor(q, o);
  float rstd = rsqrtf(q * (1.f / 768.f) + 1e-5f);
  const float* wp = w + lane * 12;
  const float* bp = b + lane * 12;
  f32x4 w0 = *(const f32x4*)(wp), w1 = *(const f32x4*)(wp + 4), w2 = *(const f32x4*)(wp + 8);
  f32x4 b0 = *(const f32x4*)(bp), b1 = *(const f32x4*)(bp + 4), b2 = *(const f32x4*)(bp + 8);
  short* orow = out + (size_t)row * 768 + lane * 12;
  s16x4 o0, o1, o2;
#pragma unroll
  for (int j = 0; j < 4; ++j) {
    o0[j] = f2bf((a0[j] - mean) * rstd * w0[j] + b0[j]);
    o1[j] = f2bf((a1[j] - mean) * rstd * w1[j] + b1[j]);
    o2[j] = f2bf((a2[j] - mean) * rstd * w2[j] + b2[j]);
  }
  *(s16x4*)(orow) = o0;
  *(s16x4*)(orow + 4) = o1;
  *(s16x4*)(orow + 8) = o2;
}

// ---------- GEMM 128x128, BK=32, depth-2 counted-vmcnt pipeline (R21-proven) ----------
template <int MODE>
__global__ __launch_bounds__(256) void gemm_bt(
    const short* __restrict__ A, const short* __restrict__ Bt,
    const float* __restrict__ bias, const float* __restrict__ res,
    void* __restrict__ out,
    short* __restrict__ dq, short* __restrict__ dk, short* __restrict__ dv,
    int M, int N, int K) {
  __shared__ short As[2][128 * 32];
  __shared__ short Bs[2][128 * 32];
  int tid = threadIdx.x;
  int lane = tid & 63;
  int wm = tid >> 7;
  int wn = (tid >> 6) & 1;
  const short* Ab = A + (size_t)blockIdx.x * 128 * K;
  const short* Bb = Bt + (size_t)blockIdx.y * 128 * K;
  f32x4 acc[4][4] = {};
  int i15 = lane & 15, g8 = (lane >> 4) << 3;
  int nk = K >> 5;
  int r0 = tid >> 2, kc = (tid & 3) << 3;

  auto stage = [&](int buf, int kt) {
    int kof = kt << 5;
    __builtin_amdgcn_global_load_lds(
        (const __attribute__((address_space(1))) unsigned*)(Ab + (size_t)r0 * K + kof + kc),
        (__attribute__((address_space(3))) unsigned*)(&As[buf][tid * 8]), 16, 0, 0);
    __builtin_amdgcn_global_load_lds(
        (const __attribute__((address_space(1))) unsigned*)(Bb + (size_t)r0 * K + kof + kc),
        (__attribute__((address_space(3))) unsigned*)(&Bs[buf][tid * 8]), 16, 0, 0);
    __builtin_amdgcn_global_load_lds(
        (const __attribute__((address_space(1))) unsigned*)(Ab + (size_t)(r0 + 64) * K + kof + kc),
        (__attribute__((address_space(3))) unsigned*)(&As[buf][(tid + 256) * 8]), 16, 0, 0);
    __builtin_amdgcn_global_load_lds(
        (const __attribute__((address_space(1))) unsigned*)(Bb + (size_t)(r0 + 64) * K + kof + kc),
        (__attribute__((address_space(3))) unsigned*)(&Bs[buf][(tid + 256) * 8]), 16, 0, 0);
  };

  stage(0, 0);
  stage(1, 1);
  int cur = 0;
  for (int kt = 0; kt < nk; ++kt) {
    if (kt + 1 < nk)
      asm volatile("s_waitcnt vmcnt(4)" ::: "memory");   // tile kt staged; kt+1 in flight
    else
      asm volatile("s_waitcnt vmcnt(0)" ::: "memory");   // tail: everything drained
    __builtin_amdgcn_s_barrier();
    __builtin_amdgcn_sched_barrier(0);
    s16x8 af[4], bfr[4];
#pragma unroll
    for (int m = 0; m < 4; ++m)
      af[m] = *(const s16x8*)(&As[cur][(wm * 64 + m * 16 + i15) * 32 + g8]);
#pragma unroll
    for (int n = 0; n < 4; ++n)
      bfr[n] = *(const s16x8*)(&Bs[cur][(wn * 64 + n * 16 + i15) * 32 + g8]);
    __builtin_amdgcn_s_setprio(1);
#pragma unroll
    for (int m = 0; m < 4; ++m)
#pragma unroll
      for (int n = 0; n < 4; ++n)
        acc[m][n] = __builtin_amdgcn_mfma_f32_16x16x32_bf16(af[m], bfr[n], acc[m][n], 0, 0, 0);
    __builtin_amdgcn_s_setprio(0);
    __builtin_amdgcn_sched_barrier(0);
    __builtin_amdgcn_s_barrier();
    if (kt + 2 < nk) stage(cur, kt + 2);
    cur ^= 1;
  }
  int row0 = blockIdx.x * 128 + wm * 64;
  int col0 = blockIdx.y * 128 + wn * 64;
  int g4 = (lane >> 4) << 2;
#pragma unroll
  for (int m = 0; m < 4; ++m) {
#pragma unroll
    for (int n = 0; n < 4; ++n) {
      int col = col0 + n * 16 + i15;
      float bv = bias[col];
      float v4[4];
#pragma unroll
      for (int r = 0; r < 4; ++r) v4[r] = acc[m][n][r] + bv;
      int rbase = row0 + m * 16 + g4;
      if constexpr (MODE == 0) {
        int sect = col / 768;            // 0=q 1=k 2=v
        int wi = col - sect * 768;
        int hh = wi >> 6, dd = wi & 63;
        int bb = rbase >> 11, tt = rbase & 2047;
        if (sect == 2) {
          s16x4 o4;
#pragma unroll
          for (int r = 0; r < 4; ++r) o4[r] = f2bf(v4[r]);
          *(s16x4*)(dv + ((size_t)(bb * H_ + hh) * D_ + dd) * T_ + tt) = o4;
        } else {
          short* dst = (sect == 0 ? dq : dk) + ((size_t)(bb * H_ + hh) * T_ + tt) * D_ + dd;
          float sc = sect == 0 ? 0.18033688f : 1.f;   // 0.125 * log2(e)
#pragma unroll
          for (int r = 0; r < 4; ++r) dst[(size_t)r * D_] = f2bf(v4[r] * sc);
        }
      } else {
#pragma unroll
        for (int r = 0; r < 4; ++r)
          ((short*)out)[(size_t)(rbase + r) * N + col] = f2bf(v4[r] > 0.f ? v4[r] : 0.f);
      }
    }
  }
}

// ---------- GEMM 64x128, BK=64 two-panel, 4-wave, depth-2 counted-vmcnt (R21-proven) ----------
__global__ __launch_bounds__(256) void gemm64_res(
    const short* __restrict__ A, const short* __restrict__ Bt,
    const float* __restrict__ bias, const float* __restrict__ res,
    float* __restrict__ out, int M, int N, int K) {
  __shared__ short As[2][2][64 * 32];
  __shared__ short Bs[2][2][128 * 32];
  int tid = threadIdx.x;
  int lane = tid & 63;
  int wv = tid >> 6;                   // wave owns cols wv*32..wv*32+31
  const short* Ab = A + (size_t)blockIdx.x * 64 * K;
  const short* Bb = Bt + (size_t)blockIdx.y * 128 * K;
  f32x4 acc[4][2] = {};
  int i15 = lane & 15, g8 = (lane >> 4) << 3;
  int nk = K >> 6;

  auto stage = [&](int buf, int kt) {
    int kof = kt << 6;
#pragma unroll
    for (int i = 0; i < 2; ++i) {      // A: 64x64 = 512 chunks, 2/thread
      int c = tid + i * 256;
      int pan = c >> 8, sp = c & 255;
      int row = sp >> 2, kk = ((sp & 3) << 3) + (pan << 5);
      __builtin_amdgcn_global_load_lds(
          (const __attribute__((address_space(1))) unsigned*)(Ab + (size_t)row * K + kof + kk),
          (__attribute__((address_space(3))) unsigned*)(&As[buf][pan][sp * 8]), 16, 0, 0);
    }
#pragma unroll
    for (int i = 0; i < 4; ++i) {      // B: 128x64 = 1024 chunks, 4/thread
      int c = tid + i * 256;
      int pan = c >> 9, sp = c & 511;
      int row = sp >> 2, kk = ((sp & 3) << 3) + (pan << 5);
      __builtin_amdgcn_global_load_lds(
          (const __attribute__((address_space(1))) unsigned*)(Bb + (size_t)row * K + kof + kk),
          (__attribute__((address_space(3))) unsigned*)(&Bs[buf][pan][sp * 8]), 16, 0, 0);
    }
  };

  stage(0, 0);
  if (nk > 1) stage(1, 1);
  int cur = 0;
  for (int kt = 0; kt < nk; ++kt) {
    if (kt + 1 < nk)
      asm volatile("s_waitcnt vmcnt(6)" ::: "memory");   // tile kt staged; kt+1 in flight
    else
      asm volatile("s_waitcnt vmcnt(0)" ::: "memory");
    __builtin_amdgcn_s_barrier();
    __builtin_amdgcn_sched_barrier(0);
#pragma unroll
    for (int h = 0; h < 2; ++h) {
      s16x8 af[4], bfr[2];
#pragma unroll
      for (int m = 0; m < 4; ++m)
        af[m] = *(const s16x8*)(&As[cur][h][(m * 16 + i15) * 32 + g8]);
#pragma unroll
      for (int n = 0; n < 2; ++n)
        bfr[n] = *(const s16x8*)(&Bs[cur][h][(wv * 32 + n * 16 + i15) * 32 + g8]);
      __builtin_amdgcn_s_setprio(1);
#pragma unroll
      for (int m = 0; m < 4; ++m)
#pragma unroll
        for (int n = 0; n < 2; ++n)
          acc[m][n] = __builtin_amdgcn_mfma_f32_16x16x32_bf16(af[m], bfr[n], acc[m][n], 0, 0, 0);
      __builtin_amdgcn_s_setprio(0);
    }
    __builtin_amdgcn_sched_barrier(0);
    __builtin_amdgcn_s_barrier();
    if (kt + 2 < nk) stage(cur, kt + 2);
    cur ^= 1;
  }
  int row0 = blockIdx.x * 64;
  int col0 = blockIdx.y * 128 + wv * 32;
  int g4 = (lane >> 4) << 2;
#pragma unroll
  for (int m = 0; m < 4; ++m) {
#pragma unroll
    for (int n = 0; n < 2; ++n) {
      int col = col0 + n * 16 + i15;
      float bv = bias[col];
      int rbase = row0 + m * 16 + g4;
#pragma unroll
      for (int r = 0; r < 4; ++r)
        out[(size_t)(rbase + r) * N + col] =
            acc[m][n][r] + bv + res[(size_t)(rbase + r) * N + col];
    }
  }
}

// ---------- causal flash attention: LDS-DMA staged + uniform pair blocks + MFMA-ones denom ----------
// (R17 structure - best measured: 70.3 us. Unchanged.)
__global__ __launch_bounds__(256) void attn_kernel(const short* __restrict__ Qb,
                                                   const short* __restrict__ Kb,
                                                   const short* __restrict__ VTb,
                                                   short* __restrict__ Ob) {
  __shared__ short Ks[2][4096];
  __shared__ short Vs[2][4096];
  int i = blockIdx.x;
  int c = i & 7, j = i >> 3;
  int p = j & 15, gy = j >> 4;
  int bh = c + (gy << 3);
  int bb = bh / H_, hh = bh - bb * H_;
  int tid = threadIdx.x, lane = tid & 63, wv = tid >> 6;
  const short* Qp = Qb + (size_t)bh * T_ * D_;
  const short* Kp = Kb + (size_t)bh * T_ * D_;
  const short* Vp = VTb + (size_t)bh * D_ * T_;
  int i15 = lane & 15, g = lane >> 4, g8 = g << 3;
  int keyA0 = ((i15 >> 2) << 3) + (i15 & 3);
  int keyB0 = keyA0 + 4;
  int fA = (keyA0 & 7) ^ ((keyA0 & 8) >> 1);
  int fB = (keyB0 & 7) ^ ((keyB0 & 8) >> 1);
  int fV = (i15 & 7) ^ ((i15 & 8) >> 1);
  int oA[2], oB[2], oV[2];
#pragma unroll
  for (int h = 0; h < 2; ++h) {
    oA[h] = keyA0 * 64 + (((h * 4 + g) ^ fA) << 3);
    oB[h] = keyB0 * 64 + (((h * 4 + g) ^ fB) << 3);
    oV[h] = i15 * 64 + (((h * 4 + g) ^ fV) << 3);
  }
  int n0 = p + 1;
  s16x8 ones;
#pragma unroll
  for (int r = 0; r < 8; ++r) ones[r] = (short)0x3F80;   // bf16 1.0
  s16x8 qf0, qf1;
  f32x4 oacc[4] = {};
  f32x4 lacc = {};
  int qrow = 0;

  auto loadQ = [&](int qb) {
    qrow = (qb << 6) + wv * 16 + i15;
    qf0 = *(const s16x8*)(Qp + (size_t)qrow * D_ + g8);
    qf1 = *(const s16x8*)(Qp + (size_t)qrow * D_ + 32 + g8);
  };
  auto stage = [&](int buf, int t) {
    int k0 = t << 6;
#pragma unroll
    for (int qq = 0; qq < 2; ++qq) {
      int m = tid + qq * 256;
      int r = m >> 3, cd = m & 7;
      int cs = cd ^ ((r & 7) ^ ((r & 8) >> 1));
      __builtin_amdgcn_global_load_lds(
          (const __attribute__((address_space(1))) unsigned*)(Kp + (size_t)(k0 + r) * D_ + (cs << 3)),
          (__attribute__((address_space(3))) unsigned*)(&Ks[buf][m * 8]), 16, 0, 0);
      __builtin_amdgcn_global_load_lds(
          (const __attribute__((address_space(1))) unsigned*)(Vp + (size_t)r * T_ + k0 + (cs << 3)),
          (__attribute__((address_space(3))) unsigned*)(&Vs[buf][m * 8]), 16, 0, 0);
    }
  };
  auto finalize = [&]() {
    float inv = 1.f / lacc[0];
    short* op = Ob + ((size_t)(bb * T_ + qrow)) * C_ + hh * D_ + (g << 2);
#pragma unroll
    for (int mt = 0; mt < 4; ++mt) {
      s16x4 o4;
#pragma unroll
      for (int r = 0; r < 4; ++r) o4[r] = f2bf(oacc[mt][r] * inv);
      *(s16x4*)(op + mt * 16) = o4;
    }
  };

  loadQ(p);
  stage(0, 0);
  __syncthreads();
  int cur = 0;
#pragma unroll 1
  for (int gt = 0; gt < 33; ++gt) {
    if (gt + 1 < 33) {
      int nkt = (gt + 1 < n0) ? (gt + 1) : (gt + 1 - n0);
      stage(cur ^ 1, nkt);
    }
    int kt = (gt < n0) ? gt : gt - n0;
    int nt = (gt < n0) ? n0 : 32 - p;
    bool diag = (kt == nt - 1);
    int k0 = kt << 6;
    const short* KB = &Ks[cur][0];
    const short* VB = &Vs[cur][0];
#pragma unroll
    for (int ks = 0; ks < 2; ++ks) {
      if (!(ks == 1 && diag && wv < 2)) {
        s16x8 ka0 = *(const s16x8*)(KB + (ks << 11) + oA[0]);
        s16x8 ka1 = *(const s16x8*)(KB + (ks << 11) + oA[1]);
        s16x8 kb0 = *(const s16x8*)(KB + (ks << 11) + oB[0]);
        s16x8 kb1 = *(const s16x8*)(KB + (ks << 11) + oB[1]);
        f32x4 sA = {}, sB = {};
        __builtin_amdgcn_s_setprio(1);
        sA = __builtin_amdgcn_mfma_f32_16x16x32_bf16(ka0, qf0, sA, 0, 0, 0);
        sA = __builtin_amdgcn_mfma_f32_16x16x32_bf16(ka1, qf1, sA, 0, 0, 0);
        sB = __builtin_amdgcn_mfma_f32_16x16x32_bf16(kb0, qf0, sB, 0, 0, 0);
        sB = __builtin_amdgcn_mfma_f32_16x16x32_bf16(kb1, qf1, sB, 0, 0, 0);
        __builtin_amdgcn_s_setprio(0);
        int kb = k0 + (ks << 5) + g8;
        float sa[8];
        bool needmask = diag && ((wv < 2) == (ks == 0));
        if (needmask) {
#pragma unroll
          for (int r = 0; r < 4; ++r) {
            sa[r]     = (kb + r     <= qrow) ? sA[r] : -1e30f;
            sa[4 + r] = (kb + 4 + r <= qrow) ? sB[r] : -1e30f;
          }
        } else {
#pragma unroll
          for (int r = 0; r < 4; ++r) { sa[r] = sA[r]; sa[4 + r] = sB[r]; }
        }
        float pv[8];
#pragma unroll
        for (int r = 0; r < 8; ++r) pv[r] = exp2f(sa[r]);
        union { unsigned u[4]; s16x8 v; } pf;
        pf.u[0] = pkbf2(pv[0], pv[1]);
        pf.u[1] = pkbf2(pv[2], pv[3]);
        pf.u[2] = pkbf2(pv[4], pv[5]);
        pf.u[3] = pkbf2(pv[6], pv[7]);
        s16x8 vf0 = *(const s16x8*)(VB + 0    + oV[ks]);
        s16x8 vf1 = *(const s16x8*)(VB + 1024 + oV[ks]);
        s16x8 vf2 = *(const s16x8*)(VB + 2048 + oV[ks]);
        s16x8 vf3 = *(const s16x8*)(VB + 3072 + oV[ks]);
        __builtin_amdgcn_s_setprio(1);
        oacc[0] = __builtin_amdgcn_mfma_f32_16x16x32_bf16(vf0, pf.v, oacc[0], 0, 0, 0);
        oacc[1] = __builtin_amdgcn_mfma_f32_16x16x32_bf16(vf1, pf.v, oacc[1], 0, 0, 0);
        oacc[2] = __builtin_amdgcn_mfma_f32_16x16x32_bf16(vf2, pf.v, oacc[2], 0, 0, 0);
        oacc[3] = __builtin_amdgcn_mfma_f32_16x16x32_bf16(vf3, pf.v, oacc[3], 0, 0, 0);
        lacc = __builtin_amdgcn_mfma_f32_16x16x32_bf16(ones, pf.v, lacc, 0, 0, 0);
        __builtin_amdgcn_s_setprio(0);
      }
    }
    if (gt == n0 - 1) {                // sub0 complete: write it, start sub1
      finalize();
      loadQ(31 - p);
#pragma unroll
      for (int mt = 0; mt < 4; ++mt) oacc[mt] = f32x4{0.f, 0.f, 0.f, 0.f};
      lacc = f32x4{0.f, 0.f, 0.f, 0.f};
    }
    __syncthreads();
    cur ^= 1;
  }
  finalize();
}

extern "C" void kernel_launch(void* const* d_in, const int* in_sizes, int n_in,
                              void* d_out, int out_size, void* d_ws, size_t ws_size,
                              hipStream_t stream) {
  const float* x     = (const float*)d_in[0];
  const float* ln1_w = (const float*)d_in[1];
  const float* ln1_b = (const float*)d_in[2];
  const float* qkv_w = (const float*)d_in[3];
  const float* qkv_b = (const float*)d_in[4];
  const float* out_w = (const float*)d_in[5];
  const float* out_b = (const float*)d_in[6];
  const float* ln2_w = (const float*)d_in[7];
  const float* ln2_b = (const float*)d_in[8];
  const float* ff1_w = (const float*)d_in[9];
  const float* ff1_b = (const float*)d_in[10];
  const float* ff2_w = (const float*)d_in[11];
  const float* ff2_b = (const float*)d_in[12];

  char* ws = (char*)d_ws;
  short* Wqkv = (short*)(ws + 0);                       // [2304,768]
  short* Wout = (short*)(ws + 3538944);                 // [768,768]
  short* Wff1 = (short*)(ws + 4718592);                 // [3072,768]
  short* Wff2 = (short*)(ws + 9437184);                 // [768,3072]
  short* Hbuf = (short*)(ws + 14155776);                // [8192,768] bf16
  short* Qb   = (short*)(ws + 26738688);                // [B,H,T,D] bf16
  short* Kb   = Qb + 6291456;
  short* VT   = Kb + 6291456;                           // [B,H,D,T] bf16 (V stored transposed)
  short* Ob   = VT + 6291456;                           // [B,T,C] bf16
  short* FFH  = Qb;                                     // alias: [8192,3072] bf16 (Q/K/V/O dead)
  float* xout = (float*)d_out;                          // also x1 residual buffer

  wconv_ln<<<8960, 256, 0, stream>>>(qkv_w, Wqkv, out_w, Wout, ff1_w, Wff1, ff2_w, Wff2,
                                     x, ln1_w, ln1_b, Hbuf);
  gemm_bt<0><<<dim3(64, 18), 256, 0, stream>>>(Hbuf, Wqkv, qkv_b, nullptr, nullptr,
                                               Qb, Kb, VT, 8192, 2304, 768);
  attn_kernel<<<768, 256, 0, stream>>>(Qb, Kb, VT, Ob);
  gemm64_res<<<dim3(128, 6), 256, 0, stream>>>(Ob, Wout, out_b, x, xout, 8192, 768, 768);
  ln_kernel<<<2048, 256, 0, stream>>>(xout, ln2_w, ln2_b, Hbuf);
  gemm_bt<2><<<dim3(64, 24), 256, 0, stream>>>(Hbuf, Wff1, ff1_b, nullptr, FFH,
                                               nullptr, nullptr, nullptr, 8192, 3072, 768);
  gemm64_res<<<dim3(128, 6), 256, 0, stream>>>(FFH, Wff2, ff2_b, xout, xout, 8192, 768, 3072);
}